// Round 17
// baseline (221.452 us; speedup 1.0000x reference)
//
#include <hip/hip_runtime.h>
#include <hip/hip_bf16.h>

#define N_NODES 50000
#define N_EDGES 800000
#define N_GRAPHS 64
#define HID 64
#define SCAN_NB 196  // ceil(50000/256)
#define FILL_RANGES 8
#define RANGE_SIZE ((N_NODES + FILL_RANGES - 1) / FILL_RANGES)  // 6250
#define MM1_BLOCKS ((N_NODES + 63) / 64)                        // 782
#define FILL_BLOCKS (FILL_RANGES * ((N_EDGES + 255) / 256))     // 25000

static inline size_t align256(size_t x) { return (x + 255) & ~(size_t)255; }

typedef __attribute__((ext_vector_type(8))) short short8v;
typedef __attribute__((ext_vector_type(4))) float f32x4;

// bf16 helpers (bit-level, RNE) -- storage compression + MFMA input prep.
__device__ __forceinline__ unsigned short f2bf(float f) {
    unsigned int u = __float_as_uint(f);
    unsigned int r = (u + 0x7fffu + ((u >> 16) & 1u)) >> 16;
    return (unsigned short)r;
}
__device__ __forceinline__ float bf2f(unsigned short h) {
    return __uint_as_float(((unsigned int)h) << 16);
}

// zero two disjoint int ranges in one launch (cnt | gsum+gmax+bflag)
__global__ void zero2(int* __restrict__ a, int na, int* __restrict__ b, int nb) {
    int i = blockIdx.x * blockDim.x + threadIdx.x;
    if (i < na) a[i] = 0;
    else if (i < na + nb) b[i - na] = 0;
}

// count incoming edges per destination node
__global__ void deg_kernel(const int* __restrict__ ei, int* __restrict__ cnt) {
    int e = blockIdx.x * blockDim.x + threadIdx.x;
    if (e < N_EDGES) atomicAdd(&cnt[ei[N_EDGES + e]], 1);
}

// FUSED scan (decoupled lookback) + row_ptr/fill_ptr/dinv writeback + gstart.
// Blocks 0..SCAN_NB-1: per-block inclusive scan of cnt; block 0 publishes its
// prefix (flag 2); others publish aggregate (flag 1), spin-lookback over
// predecessors, then publish prefix. 196 blocks are all co-resident (<=256
// CUs) so spinning cannot deadlock. bflag is zeroed each call by zero2
// (graph-replay safe). Block SCAN_NB: gstart binary searches (batch sorted).
__global__ __launch_bounds__(256) void scan_fused(const int* __restrict__ cnt,
                                                  int* __restrict__ row_ptr,
                                                  int* __restrict__ fill_ptr,
                                                  float* __restrict__ dinv,
                                                  int* __restrict__ bagg,
                                                  int* __restrict__ bpre,
                                                  int* __restrict__ bflag,
                                                  const int* __restrict__ batch,
                                                  int* __restrict__ gstart) {
    int b = blockIdx.x;
    int t = threadIdx.x;
    if (b == SCAN_NB) {
        if (t <= N_GRAPHS) {
            int g = t;
            int lo = 0, hi = N_NODES;
            while (lo < hi) {
                int mid = (lo + hi) >> 1;
                if (batch[mid] < g) lo = mid + 1; else hi = mid;
            }
            gstart[g] = lo;
        }
        return;
    }
    __shared__ int sd[256];
    __shared__ int s_exc;
    int i = b * 256 + t;
    int v = (i < N_NODES) ? cnt[i] : 0;
    sd[t] = v;
    __syncthreads();
    for (int off = 1; off < 256; off <<= 1) {
        int u = (t >= off) ? sd[t - off] : 0;
        __syncthreads();
        sd[t] += u;
        __syncthreads();
    }
    int incl = sd[t];
    int total = sd[255];
    if (t == 0) {
        if (b == 0) {
            bpre[0] = total;
            __threadfence();
            atomicExch(&bflag[0], 2);
            s_exc = 0;
        } else {
            bagg[b] = total;
            __threadfence();
            atomicExch(&bflag[b], 1);
            int run = 0;
            int j = b - 1;
            while (true) {
                int f;
                do { f = atomicAdd(&bflag[j], 0); } while (f == 0);
                if (f == 2) { run += atomicAdd(&bpre[j], 0); break; }
                run += atomicAdd(&bagg[j], 0);
                --j;
            }
            bpre[b] = run + total;
            __threadfence();
            atomicExch(&bflag[b], 2);
            s_exc = run;
        }
    }
    __syncthreads();
    int exc = s_exc;
    if (i < N_NODES) {
        int run = exc + incl;              // inclusive global prefix
        row_ptr[i + 1] = run;
        fill_ptr[i] = run - v;             // bucket start
        dinv[i] = rsqrtf((float)v + 1.0f);
        if (i == 0) row_ptr[0] = 0;
    }
}

// DUAL-ROLE kernel: blocks [0, MM1_BLOCKS) run the layer-1 MFMA matmul;
// blocks [MM1_BLOCKS, ...) run the XCD-partitioned CSR scatter (round-8
// lesson: partition dst ranges so each csr region is written from one XCD;
// class (bid-MM1_BLOCKS)&7 is a fixed bid%8 residue). csr_src is uint16
// (src < 65536): halves scatter bytes and dirty-line count (round-16).
// MM part: hw2 = bf16(dinv * (x @ W1)), 3-term hi/lo bf16 split; W fragments
// pre-swizzled in LDS; D layout (m89): row=(l>>4)*4+j, col=l&15.
__global__ __launch_bounds__(256) void fill_mm1_kernel(const int* __restrict__ ei,
                                                       int* __restrict__ fill_ptr,
                                                       unsigned short* __restrict__ csr_src,
                                                       const float* __restrict__ h,
                                                       const float* __restrict__ W,
                                                       const float* __restrict__ dinv,
                                                       unsigned short* __restrict__ hw2) {
    constexpr int K = 128;
    constexpr int NSTEP = K / 32;
    __shared__ unsigned short sWH[NSTEP * 4 * 64 * 8];
    __shared__ unsigned short sWL[NSTEP * 4 * 64 * 8];
    int tid = threadIdx.x;

    if (blockIdx.x >= MM1_BLOCKS) {
        // ---- fill role ----
        int fb = blockIdx.x - MM1_BLOCKS;
        int r = fb & (FILL_RANGES - 1);
        int e = (fb >> 3) * 256 + tid;
        if (e >= N_EDGES) return;
        int dst = ei[N_EDGES + e];
        int lo = r * RANGE_SIZE;
        if (dst >= lo && dst < lo + RANGE_SIZE) {
            int src = ei[e];
            int pos = atomicAdd(&fill_ptr[dst], 1);
            csr_src[pos] = (unsigned short)src;
        }
        return;
    }

    // ---- mm role ----
    int r0 = blockIdx.x * 64;
#pragma unroll 1
    for (int ent = tid; ent < NSTEP * 4 * 64; ent += 256) {
        int lane_e = ent & 63;
        int c = (ent >> 6) & 3;
        int step = ent >> 8;
        int kb = step * 32 + (lane_e >> 4) * 8;
        int n = c * 16 + (lane_e & 15);
#pragma unroll
        for (int j = 0; j < 8; ++j) {
            float f = W[(kb + j) * 64 + n];
            unsigned short hi = f2bf(f);
            sWH[ent * 8 + j] = hi;
            sWL[ent * 8 + j] = f2bf(f - bf2f(hi));
        }
    }
    __syncthreads();

    int lane = tid & 63;
    int wid = tid >> 6;
    int arow = min(r0 + wid * 16 + (lane & 15), N_NODES - 1);  // clamp; write guarded
    const float* ap = h + (size_t)arow * K;
    int klane = (lane >> 4) * 8;

    f32x4 acc[4];
#pragma unroll
    for (int c = 0; c < 4; ++c) acc[c] = (f32x4){0.f, 0.f, 0.f, 0.f};

#pragma unroll 1
    for (int step = 0; step < NSTEP; ++step) {
        int kb = step * 32 + klane;
        float4 f0 = *(const float4*)&ap[kb];
        float4 f1 = *(const float4*)&ap[kb + 4];
        float fv[8] = {f0.x, f0.y, f0.z, f0.w, f1.x, f1.y, f1.z, f1.w};
        short8v ahi, alo;
#pragma unroll
        for (int j = 0; j < 8; ++j) {
            unsigned short hi = f2bf(fv[j]);
            ahi[j] = (short)hi;
            alo[j] = (short)f2bf(fv[j] - bf2f(hi));
        }
#pragma unroll
        for (int c = 0; c < 4; ++c) {
            short8v bh = *(const short8v*)&sWH[((step * 4 + c) * 64 + lane) * 8];
            short8v bl = *(const short8v*)&sWL[((step * 4 + c) * 64 + lane) * 8];
            acc[c] = __builtin_amdgcn_mfma_f32_16x16x32_bf16(ahi, bh, acc[c], 0, 0, 0);
            acc[c] = __builtin_amdgcn_mfma_f32_16x16x32_bf16(alo, bh, acc[c], 0, 0, 0);
            acc[c] = __builtin_amdgcn_mfma_f32_16x16x32_bf16(ahi, bl, acc[c], 0, 0, 0);
        }
    }

    int rb = r0 + wid * 16 + (lane >> 4) * 4;
#pragma unroll
    for (int j = 0; j < 4; ++j) {
        int row = rb + j;
        if (row < N_NODES) {
            float dv = dinv[row];
#pragma unroll
            for (int c = 0; c < 4; ++c) {
                hw2[(size_t)row * 64 + c * 16 + (lane & 15)] = f2bf(dv * acc[c][j]);
            }
        }
    }
}

// MFMA matmul (layers 2/3, K=64): same scheme as the mm role above.
// Round-12 lesson: keep separate from the gather kernel.
template <int K>
__global__ __launch_bounds__(256) void mfma_matmul(const float* __restrict__ h,
                                                   const float* __restrict__ W,
                                                   const float* __restrict__ dinv,
                                                   unsigned short* __restrict__ hw2) {
    constexpr int NSTEP = K / 32;
    __shared__ unsigned short sWH[NSTEP * 4 * 64 * 8];
    __shared__ unsigned short sWL[NSTEP * 4 * 64 * 8];
    int tid = threadIdx.x;
    int r0 = blockIdx.x * 64;

#pragma unroll 1
    for (int ent = tid; ent < NSTEP * 4 * 64; ent += 256) {
        int lane_e = ent & 63;
        int c = (ent >> 6) & 3;
        int step = ent >> 8;
        int kb = step * 32 + (lane_e >> 4) * 8;
        int n = c * 16 + (lane_e & 15);
#pragma unroll
        for (int j = 0; j < 8; ++j) {
            float f = W[(kb + j) * 64 + n];
            unsigned short hi = f2bf(f);
            sWH[ent * 8 + j] = hi;
            sWL[ent * 8 + j] = f2bf(f - bf2f(hi));
        }
    }
    __syncthreads();

    int lane = tid & 63;
    int wid = tid >> 6;
    int arow = min(r0 + wid * 16 + (lane & 15), N_NODES - 1);  // clamp; write guarded
    const float* ap = h + (size_t)arow * K;
    int klane = (lane >> 4) * 8;

    f32x4 acc[4];
#pragma unroll
    for (int c = 0; c < 4; ++c) acc[c] = (f32x4){0.f, 0.f, 0.f, 0.f};

#pragma unroll 1
    for (int step = 0; step < NSTEP; ++step) {
        int kb = step * 32 + klane;
        float4 f0 = *(const float4*)&ap[kb];
        float4 f1 = *(const float4*)&ap[kb + 4];
        float fv[8] = {f0.x, f0.y, f0.z, f0.w, f1.x, f1.y, f1.z, f1.w};
        short8v ahi, alo;
#pragma unroll
        for (int j = 0; j < 8; ++j) {
            unsigned short hi = f2bf(fv[j]);
            ahi[j] = (short)hi;
            alo[j] = (short)f2bf(fv[j] - bf2f(hi));
        }
#pragma unroll
        for (int c = 0; c < 4; ++c) {
            short8v bh = *(const short8v*)&sWH[((step * 4 + c) * 64 + lane) * 8];
            short8v bl = *(const short8v*)&sWL[((step * 4 + c) * 64 + lane) * 8];
            acc[c] = __builtin_amdgcn_mfma_f32_16x16x32_bf16(ahi, bh, acc[c], 0, 0, 0);
            acc[c] = __builtin_amdgcn_mfma_f32_16x16x32_bf16(alo, bh, acc[c], 0, 0, 0);
            acc[c] = __builtin_amdgcn_mfma_f32_16x16x32_bf16(ahi, bl, acc[c], 0, 0, 0);
        }
    }

    int rb = r0 + wid * 16 + (lane >> 4) * 4;
#pragma unroll
    for (int j = 0; j < 4; ++j) {
        int row = rb + j;
        if (row < N_NODES) {
            float dv = dinv[row];
#pragma unroll
            for (int c = 0; c < 4; ++c) {
                hw2[(size_t)row * 64 + c * 16 + (lane & 15)] = f2bf(dv * acc[c][j]);
            }
        }
    }
}

// per node (one wave): 8 edges in flight (round-14: 8-wide is the sweet spot).
// Inner loop unrolled into 8 wave-uniform-gated rounds with always-executed
// loads at a safe clamped address (explicit MLP; round-16). csr_src is u16.
// shfl trip count wave-uniform (round-5 lesson).
// POOL=true (layer 3): block's 4 nodes -> LDS, 64 threads run-combine per dim
// (batch sorted), ~1 atomicAdd+atomicMax per dim per block. Grid exactly
// N_NODES/4 (no tail; all threads reach the barrier).
template <bool POOL>
__global__ __launch_bounds__(256) void agg_kernel(const unsigned short* __restrict__ hw2,
                                                  const int* __restrict__ row_ptr,
                                                  const unsigned short* __restrict__ csr_src,
                                                  const float* __restrict__ dinv,
                                                  const float* __restrict__ b,
                                                  float* __restrict__ hout,
                                                  const int* __restrict__ batch,
                                                  float* __restrict__ gsum,
                                                  float* __restrict__ gmax) {
    __shared__ float sh[4][64];  // POOL only
    int tid = threadIdx.x;
    int node = blockIdx.x * 4 + (tid >> 6);   // grid exact: node < N_NODES always
    int lane = tid & 63;
    int grp = lane >> 3;   // 0..7 : which edge of the 8-wide batch
    int gl  = lane & 7;    // 0..7 : dims 8*gl .. 8*gl+7
    int s = row_ptr[node], e = row_ptr[node + 1];

    float acc[8] = {0.f, 0.f, 0.f, 0.f, 0.f, 0.f, 0.f, 0.f};
    for (int base = s; base < e; base += 64) {
        int nE = min(64, e - base);                                  // wave-uniform
        int msrc = (lane < nE) ? (int)csr_src[base + lane] : 0;      // coalesced u16
#pragma unroll
        for (int rr = 0; rr < 8; ++rr) {
            int i = rr * 8;
            if (i >= nE) break;                              // wave-uniform exit
            int myi = i + grp;                               // <= 63 always
            int src = __shfl(msrc, myi, 64);                 // full-exec shfl
            bool ok = myi < nE;
            int srcx = ok ? src : node;                      // safe, L2-hot fallback
            short8v v = *(const short8v*)&hw2[(size_t)srcx * 64 + gl * 8];
            if (ok) {
#pragma unroll
                for (int j = 0; j < 8; ++j) acc[j] += bf2f((unsigned short)v[j]);
            }
        }
    }
    // sum the 8 groups' partials (dims aligned across groups)
#pragma unroll
    for (int off = 8; off <= 32; off <<= 1) {
#pragma unroll
        for (int j = 0; j < 8; ++j) acc[j] += __shfl_xor(acc[j], off, 64);
    }
    // self-loop term (hw2 pre-scaled by dinv[row])
    short8v sv = *(const short8v*)&hw2[(size_t)node * 64 + gl * 8];
#pragma unroll
    for (int j = 0; j < 8; ++j) acc[j] += bf2f((unsigned short)sv[j]);

    float di = dinv[node];
    float4 b0 = *(const float4*)&b[gl * 8];
    float4 b1 = *(const float4*)&b[gl * 8 + 4];
    float val[8];
    val[0] = di * acc[0] + b0.x;
    val[1] = di * acc[1] + b0.y;
    val[2] = di * acc[2] + b0.z;
    val[3] = di * acc[3] + b0.w;
    val[4] = di * acc[4] + b1.x;
    val[5] = di * acc[5] + b1.y;
    val[6] = di * acc[6] + b1.z;
    val[7] = di * acc[7] + b1.w;

    float sq = 0.f;
#pragma unroll
    for (int j = 0; j < 8; ++j) sq += val[j] * val[j];
#pragma unroll
    for (int off = 1; off <= 4; off <<= 1) sq += __shfl_xor(sq, off, 64);
    float inv = 1.0f / fmaxf(sqrtf(sq), 1e-12f);

    if (POOL) {
        if (grp == 0) {
            float4 r0, r1;
            r0.x = fmaxf(val[0] * inv, 0.f);
            r0.y = fmaxf(val[1] * inv, 0.f);
            r0.z = fmaxf(val[2] * inv, 0.f);
            r0.w = fmaxf(val[3] * inv, 0.f);
            r1.x = fmaxf(val[4] * inv, 0.f);
            r1.y = fmaxf(val[5] * inv, 0.f);
            r1.z = fmaxf(val[6] * inv, 0.f);
            r1.w = fmaxf(val[7] * inv, 0.f);
            *(float4*)&sh[tid >> 6][gl * 8] = r0;
            *(float4*)&sh[tid >> 6][gl * 8 + 4] = r1;
        }
        __syncthreads();
        if (tid < 64) {
            int nb = blockIdx.x * 4;
            int gcur = batch[nb];
            float runsum = 0.f, runmax = 0.f;
#pragma unroll
            for (int w = 0; w < 4; ++w) {
                int g = batch[nb + w];
                if (g != gcur) {
                    atomicAdd(&gsum[gcur * 64 + tid], runsum);
                    atomicMax((int*)&gmax[gcur * 64 + tid], __float_as_int(runmax));
                    runsum = 0.f; runmax = 0.f; gcur = g;
                }
                float v = sh[w][tid];
                runsum += v;
                runmax = fmaxf(runmax, v);
            }
            atomicAdd(&gsum[gcur * 64 + tid], runsum);
            atomicMax((int*)&gmax[gcur * 64 + tid], __float_as_int(runmax));
        }
    } else {
        if (grp == 0) {
            float4 r0, r1;
            r0.x = fmaxf(val[0] * inv, 0.f);
            r0.y = fmaxf(val[1] * inv, 0.f);
            r0.z = fmaxf(val[2] * inv, 0.f);
            r0.w = fmaxf(val[3] * inv, 0.f);
            r1.x = fmaxf(val[4] * inv, 0.f);
            r1.y = fmaxf(val[5] * inv, 0.f);
            r1.z = fmaxf(val[6] * inv, 0.f);
            r1.w = fmaxf(val[7] * inv, 0.f);
            *(float4*)&hout[(size_t)node * 64 + gl * 8] = r0;
            *(float4*)&hout[(size_t)node * 64 + gl * 8 + 4] = r1;
        }
    }
}

// Phase-2: one block per graph; mean + concat + 128x32 linear.
__global__ __launch_bounds__(128) void linear_kernel(const float* __restrict__ gsum,
                                                     const float* __restrict__ gmax,
                                                     const int* __restrict__ gstart,
                                                     const float* __restrict__ Wl,
                                                     const float* __restrict__ bl,
                                                     float* __restrict__ out) {
    int g = blockIdx.x;
    __shared__ float pooled[128];
    int t = threadIdx.x;
    if (t < 64) {
        int cnt = gstart[g + 1] - gstart[g];
        pooled[t] = gsum[g * 64 + t] / fmaxf((float)cnt, 1.0f);
    } else {
        pooled[t] = gmax[g * 64 + (t - 64)];
    }
    __syncthreads();
    if (t < 32) {
        float acc = bl[t];
#pragma unroll 8
        for (int k = 0; k < 128; ++k) acc += pooled[k] * Wl[k * 32 + t];
        out[g * 32 + t] = acc;
    }
}

extern "C" void kernel_launch(void* const* d_in, const int* in_sizes, int n_in,
                              void* d_out, int out_size, void* d_ws, size_t ws_size,
                              hipStream_t stream) {
    const float* x        = (const float*)d_in[0];   // 50000 x 128
    const int*   ei       = (const int*)d_in[1];     // 2 x 800000
    const int*   batch    = (const int*)d_in[2];     // 50000
    const float* W1       = (const float*)d_in[3];   // 128 x 64
    const float* b1       = (const float*)d_in[4];
    const float* W2       = (const float*)d_in[5];   // 64 x 64
    const float* b2       = (const float*)d_in[6];
    const float* W3       = (const float*)d_in[7];   // 64 x 64
    const float* b3       = (const float*)d_in[8];
    const float* Wl       = (const float*)d_in[9];   // 128 x 32
    const float* bl       = (const float*)d_in[10];
    float* out = (float*)d_out;

    char* ws = (char*)d_ws;
    int*   cnt      = (int*)ws;                 ws += align256((size_t)N_NODES * 4);
    int*   row_ptr  = (int*)ws;                 ws += align256((size_t)(N_NODES + 1) * 4);
    int*   fill_ptr = (int*)ws;                 ws += align256((size_t)N_NODES * 4);
    float* dinv     = (float*)ws;               ws += align256((size_t)N_NODES * 4);
    int*   gstart   = (int*)ws;                 ws += align256((size_t)(N_GRAPHS + 1) * 4);
    // gsum | gmax | bflag contiguous: one zero2 range covers all three
    float* gsum     = (float*)ws;               ws += (size_t)N_GRAPHS * 64 * 4;   // 16384 (256-mult)
    float* gmax     = (float*)ws;               ws += (size_t)N_GRAPHS * 64 * 4;   // 16384
    int*   bflag    = (int*)ws;                 ws += align256((size_t)SCAN_NB * 4);
    int*   bagg     = (int*)ws;                 ws += align256((size_t)SCAN_NB * 4);
    int*   bpre     = (int*)ws;                 ws += align256((size_t)SCAN_NB * 4);
    unsigned short* csr_src = (unsigned short*)ws; ws += align256((size_t)N_EDGES * 2);
    unsigned short* hwb = (unsigned short*)ws;  ws += align256((size_t)N_NODES * 64 * 2);
    float* h1       = (float*)ws;               ws += align256((size_t)N_NODES * 64 * 4);
    float* h2       = (float*)ws;               ws += align256((size_t)N_NODES * 64 * 4);

    const int nzero2 = 2 * N_GRAPHS * 64 + SCAN_NB;  // gsum+gmax+bflag
    hipLaunchKernelGGL(zero2, dim3((N_NODES + nzero2 + 255) / 256), dim3(256), 0,
                       stream, cnt, N_NODES, (int*)gsum, nzero2);
    hipLaunchKernelGGL(deg_kernel, dim3((N_EDGES + 255) / 256), dim3(256), 0, stream, ei, cnt);
    hipLaunchKernelGGL(scan_fused, dim3(SCAN_NB + 1), dim3(256), 0, stream,
                       cnt, row_ptr, fill_ptr, dinv, bagg, bpre, bflag, batch, gstart);

    const int mm_grid = (N_NODES + 63) / 64;
    const int agg_grid = N_NODES / 4;  // exact: 12500 * 4 == 50000 (POOL needs no tail)

    // fill (CSR scatter, u16) and layer-1 matmul overlap in one dual-role launch
    hipLaunchKernelGGL(fill_mm1_kernel, dim3(MM1_BLOCKS + FILL_BLOCKS), dim3(256), 0, stream,
                       ei, fill_ptr, csr_src, x, W1, dinv, hwb);

    hipLaunchKernelGGL((agg_kernel<false>), dim3(agg_grid), dim3(256), 0, stream,
                       hwb, row_ptr, csr_src, dinv, b1, h1, batch, gsum, gmax);
    // layer 2
    hipLaunchKernelGGL((mfma_matmul<64>), dim3(mm_grid), dim3(256), 0, stream, h1, W2, dinv, hwb);
    hipLaunchKernelGGL((agg_kernel<false>), dim3(agg_grid), dim3(256), 0, stream,
                       hwb, row_ptr, csr_src, dinv, b2, h2, batch, gsum, gmax);
    // layer 3: matmul then fused agg+pool
    hipLaunchKernelGGL((mfma_matmul<64>), dim3(mm_grid), dim3(256), 0, stream, h2, W3, dinv, hwb);
    hipLaunchKernelGGL((agg_kernel<true>), dim3(agg_grid), dim3(256), 0, stream,
                       hwb, row_ptr, csr_src, dinv, b3, (float*)nullptr, batch, gsum, gmax);

    // final linear
    hipLaunchKernelGGL(linear_kernel, dim3(N_GRAPHS), dim3(128), 0, stream,
                       gsum, gmax, gstart, Wl, bl, out);
}

// Round 18
// 208.791 us; speedup vs baseline: 1.0606x; 1.0606x over previous
//
#include <hip/hip_runtime.h>
#include <hip/hip_bf16.h>

#define N_NODES 50000
#define N_EDGES 800000
#define N_GRAPHS 64
#define HID 64
#define SCAN_NB 196  // ceil(50000/256)
#define FILL_RANGES 8
#define RANGE_SIZE ((N_NODES + FILL_RANGES - 1) / FILL_RANGES)  // 6250
#define MM1_BLOCKS ((N_NODES + 63) / 64)                        // 782
#define FILL_BLOCKS (FILL_RANGES * ((N_EDGES + 255) / 256))     // 25000

static inline size_t align256(size_t x) { return (x + 255) & ~(size_t)255; }

typedef __attribute__((ext_vector_type(8))) short short8v;
typedef __attribute__((ext_vector_type(4))) float f32x4;

// bf16 helpers (bit-level, RNE) -- storage compression + MFMA input prep.
__device__ __forceinline__ unsigned short f2bf(float f) {
    unsigned int u = __float_as_uint(f);
    unsigned int r = (u + 0x7fffu + ((u >> 16) & 1u)) >> 16;
    return (unsigned short)r;
}
__device__ __forceinline__ float bf2f(unsigned short h) {
    return __uint_as_float(((unsigned int)h) << 16);
}

// zero two disjoint int ranges in one launch (cnt | gsum+gmax)
__global__ void zero2(int* __restrict__ a, int na, int* __restrict__ b, int nb) {
    int i = blockIdx.x * blockDim.x + threadIdx.x;
    if (i < na) a[i] = 0;
    else if (i < na + nb) b[i - na] = 0;
}

// count incoming edges per destination node
__global__ void deg_kernel(const int* __restrict__ ei, int* __restrict__ cnt) {
    int e = blockIdx.x * blockDim.x + threadIdx.x;
    if (e < N_EDGES) atomicAdd(&cnt[ei[N_EDGES + e]], 1);
}

// phase A: per-block (256-wide) inclusive scan of cnt; block totals to bsum
// (round-17 lesson: decoupled-lookback single-kernel scan serializes through
// a device-atomic chain and cost +14us; the 3 tiny grid-parallel launches win)
__global__ __launch_bounds__(256) void scan_a(const int* __restrict__ cnt,
                                              int* __restrict__ incl,
                                              int* __restrict__ bsum) {
    __shared__ int sd[256];
    int t = threadIdx.x;
    int i = blockIdx.x * 256 + t;
    int v = (i < N_NODES) ? cnt[i] : 0;
    sd[t] = v;
    __syncthreads();
    for (int off = 1; off < 256; off <<= 1) {
        int u = (t >= off) ? sd[t - off] : 0;
        __syncthreads();
        sd[t] += u;
        __syncthreads();
    }
    if (i < N_NODES) incl[i] = sd[t];
    if (t == 255) bsum[blockIdx.x] = sd[255];
}

// phase B (+gstart fused): threads 0..255 scan the block sums; threads
// 256..320 binary-search gstart (batch sorted). All threads hit every barrier.
__global__ __launch_bounds__(384) void scan_b_gstart(const int* __restrict__ bsum,
                                                     int* __restrict__ boff,
                                                     const int* __restrict__ batch,
                                                     int* __restrict__ gstart) {
    __shared__ int sd[256];
    int t = threadIdx.x;
    int v = 0;
    if (t < 256) {
        v = (t < SCAN_NB) ? bsum[t] : 0;
        sd[t] = v;
    }
    __syncthreads();
    for (int off = 1; off < 256; off <<= 1) {
        int u = (t < 256 && t >= off) ? sd[t - off] : 0;
        __syncthreads();
        if (t < 256) sd[t] += u;
        __syncthreads();
    }
    if (t < SCAN_NB) boff[t] = sd[t] - v;  // exclusive
    if (t >= 256 && t - 256 <= N_GRAPHS) {
        int g = t - 256;
        int lo = 0, hi = N_NODES;
        while (lo < hi) {
            int mid = (lo + hi) >> 1;
            if (batch[mid] < g) lo = mid + 1; else hi = mid;
        }
        gstart[g] = lo;
    }
}

// phase C: writeback row_ptr / fill_ptr / dinv
__global__ void scan_c(const int* __restrict__ cnt, const int* __restrict__ incl,
                       const int* __restrict__ boff, int* __restrict__ row_ptr,
                       int* __restrict__ fill_ptr, float* __restrict__ dinv) {
    int i = blockIdx.x * blockDim.x + threadIdx.x;
    if (i < N_NODES) {
        int c = cnt[i];
        int run = boff[i >> 8] + incl[i];  // inclusive prefix over all nodes
        row_ptr[i + 1] = run;
        fill_ptr[i] = run - c;             // bucket start
        dinv[i] = rsqrtf((float)c + 1.0f);
        if (i == 0) row_ptr[0] = 0;
    }
}

// DUAL-ROLE kernel: blocks [0, MM1_BLOCKS) run the layer-1 MFMA matmul;
// blocks [MM1_BLOCKS, ...) run the XCD-partitioned CSR scatter (round-8
// lesson: partition dst ranges so each csr region is written from one XCD;
// class (bid-MM1_BLOCKS)&7 is a fixed bid%8 residue). csr_src is uint16
// (src < 65536): halves scatter bytes + agg index reads (round-17: neutral
// on fill writeback, slight win on agg).
// MM part: hw2 = bf16(dinv * (x @ W1)), 3-term hi/lo bf16 split; W fragments
// pre-swizzled in LDS; D layout (m89): row=(l>>4)*4+j, col=l&15.
__global__ __launch_bounds__(256) void fill_mm1_kernel(const int* __restrict__ ei,
                                                       int* __restrict__ fill_ptr,
                                                       unsigned short* __restrict__ csr_src,
                                                       const float* __restrict__ h,
                                                       const float* __restrict__ W,
                                                       const float* __restrict__ dinv,
                                                       unsigned short* __restrict__ hw2) {
    constexpr int K = 128;
    constexpr int NSTEP = K / 32;
    __shared__ unsigned short sWH[NSTEP * 4 * 64 * 8];
    __shared__ unsigned short sWL[NSTEP * 4 * 64 * 8];
    int tid = threadIdx.x;

    if (blockIdx.x >= MM1_BLOCKS) {
        // ---- fill role ----
        int fb = blockIdx.x - MM1_BLOCKS;
        int r = fb & (FILL_RANGES - 1);
        int e = (fb >> 3) * 256 + tid;
        if (e >= N_EDGES) return;
        int dst = ei[N_EDGES + e];
        int lo = r * RANGE_SIZE;
        if (dst >= lo && dst < lo + RANGE_SIZE) {
            int src = ei[e];
            int pos = atomicAdd(&fill_ptr[dst], 1);
            csr_src[pos] = (unsigned short)src;
        }
        return;
    }

    // ---- mm role ----
    int r0 = blockIdx.x * 64;
#pragma unroll 1
    for (int ent = tid; ent < NSTEP * 4 * 64; ent += 256) {
        int lane_e = ent & 63;
        int c = (ent >> 6) & 3;
        int step = ent >> 8;
        int kb = step * 32 + (lane_e >> 4) * 8;
        int n = c * 16 + (lane_e & 15);
#pragma unroll
        for (int j = 0; j < 8; ++j) {
            float f = W[(kb + j) * 64 + n];
            unsigned short hi = f2bf(f);
            sWH[ent * 8 + j] = hi;
            sWL[ent * 8 + j] = f2bf(f - bf2f(hi));
        }
    }
    __syncthreads();

    int lane = tid & 63;
    int wid = tid >> 6;
    int arow = min(r0 + wid * 16 + (lane & 15), N_NODES - 1);  // clamp; write guarded
    const float* ap = h + (size_t)arow * K;
    int klane = (lane >> 4) * 8;

    f32x4 acc[4];
#pragma unroll
    for (int c = 0; c < 4; ++c) acc[c] = (f32x4){0.f, 0.f, 0.f, 0.f};

#pragma unroll 1
    for (int step = 0; step < NSTEP; ++step) {
        int kb = step * 32 + klane;
        float4 f0 = *(const float4*)&ap[kb];
        float4 f1 = *(const float4*)&ap[kb + 4];
        float fv[8] = {f0.x, f0.y, f0.z, f0.w, f1.x, f1.y, f1.z, f1.w};
        short8v ahi, alo;
#pragma unroll
        for (int j = 0; j < 8; ++j) {
            unsigned short hi = f2bf(fv[j]);
            ahi[j] = (short)hi;
            alo[j] = (short)f2bf(fv[j] - bf2f(hi));
        }
#pragma unroll
        for (int c = 0; c < 4; ++c) {
            short8v bh = *(const short8v*)&sWH[((step * 4 + c) * 64 + lane) * 8];
            short8v bl = *(const short8v*)&sWL[((step * 4 + c) * 64 + lane) * 8];
            acc[c] = __builtin_amdgcn_mfma_f32_16x16x32_bf16(ahi, bh, acc[c], 0, 0, 0);
            acc[c] = __builtin_amdgcn_mfma_f32_16x16x32_bf16(alo, bh, acc[c], 0, 0, 0);
            acc[c] = __builtin_amdgcn_mfma_f32_16x16x32_bf16(ahi, bl, acc[c], 0, 0, 0);
        }
    }

    int rb = r0 + wid * 16 + (lane >> 4) * 4;
#pragma unroll
    for (int j = 0; j < 4; ++j) {
        int row = rb + j;
        if (row < N_NODES) {
            float dv = dinv[row];
#pragma unroll
            for (int c = 0; c < 4; ++c) {
                hw2[(size_t)row * 64 + c * 16 + (lane & 15)] = f2bf(dv * acc[c][j]);
            }
        }
    }
}

// MFMA matmul (layers 2/3, K=64): same scheme as the mm role above.
// Round-12 lesson: keep separate from the gather kernel.
template <int K>
__global__ __launch_bounds__(256) void mfma_matmul(const float* __restrict__ h,
                                                   const float* __restrict__ W,
                                                   const float* __restrict__ dinv,
                                                   unsigned short* __restrict__ hw2) {
    constexpr int NSTEP = K / 32;
    __shared__ unsigned short sWH[NSTEP * 4 * 64 * 8];
    __shared__ unsigned short sWL[NSTEP * 4 * 64 * 8];
    int tid = threadIdx.x;
    int r0 = blockIdx.x * 64;

#pragma unroll 1
    for (int ent = tid; ent < NSTEP * 4 * 64; ent += 256) {
        int lane_e = ent & 63;
        int c = (ent >> 6) & 3;
        int step = ent >> 8;
        int kb = step * 32 + (lane_e >> 4) * 8;
        int n = c * 16 + (lane_e & 15);
#pragma unroll
        for (int j = 0; j < 8; ++j) {
            float f = W[(kb + j) * 64 + n];
            unsigned short hi = f2bf(f);
            sWH[ent * 8 + j] = hi;
            sWL[ent * 8 + j] = f2bf(f - bf2f(hi));
        }
    }
    __syncthreads();

    int lane = tid & 63;
    int wid = tid >> 6;
    int arow = min(r0 + wid * 16 + (lane & 15), N_NODES - 1);  // clamp; write guarded
    const float* ap = h + (size_t)arow * K;
    int klane = (lane >> 4) * 8;

    f32x4 acc[4];
#pragma unroll
    for (int c = 0; c < 4; ++c) acc[c] = (f32x4){0.f, 0.f, 0.f, 0.f};

#pragma unroll 1
    for (int step = 0; step < NSTEP; ++step) {
        int kb = step * 32 + klane;
        float4 f0 = *(const float4*)&ap[kb];
        float4 f1 = *(const float4*)&ap[kb + 4];
        float fv[8] = {f0.x, f0.y, f0.z, f0.w, f1.x, f1.y, f1.z, f1.w};
        short8v ahi, alo;
#pragma unroll
        for (int j = 0; j < 8; ++j) {
            unsigned short hi = f2bf(fv[j]);
            ahi[j] = (short)hi;
            alo[j] = (short)f2bf(fv[j] - bf2f(hi));
        }
#pragma unroll
        for (int c = 0; c < 4; ++c) {
            short8v bh = *(const short8v*)&sWH[((step * 4 + c) * 64 + lane) * 8];
            short8v bl = *(const short8v*)&sWL[((step * 4 + c) * 64 + lane) * 8];
            acc[c] = __builtin_amdgcn_mfma_f32_16x16x32_bf16(ahi, bh, acc[c], 0, 0, 0);
            acc[c] = __builtin_amdgcn_mfma_f32_16x16x32_bf16(alo, bh, acc[c], 0, 0, 0);
            acc[c] = __builtin_amdgcn_mfma_f32_16x16x32_bf16(ahi, bl, acc[c], 0, 0, 0);
        }
    }

    int rb = r0 + wid * 16 + (lane >> 4) * 4;
#pragma unroll
    for (int j = 0; j < 4; ++j) {
        int row = rb + j;
        if (row < N_NODES) {
            float dv = dinv[row];
#pragma unroll
            for (int c = 0; c < 4; ++c) {
                hw2[(size_t)row * 64 + c * 16 + (lane & 15)] = f2bf(dv * acc[c][j]);
            }
        }
    }
}

// per node (one wave): 8 edges in flight (round-14: 8-wide is the sweet spot).
// Inner loop unrolled into 8 wave-uniform-gated rounds with always-executed
// loads at a safe clamped address (explicit MLP; round-16). csr_src is u16.
// shfl trip count wave-uniform (round-5 lesson).
// POOL=true (layer 3): block's 4 nodes -> LDS, 64 threads run-combine per dim
// (batch sorted), ~1 atomicAdd+atomicMax per dim per block. Grid exactly
// N_NODES/4 (no tail; all threads reach the barrier).
template <bool POOL>
__global__ __launch_bounds__(256) void agg_kernel(const unsigned short* __restrict__ hw2,
                                                  const int* __restrict__ row_ptr,
                                                  const unsigned short* __restrict__ csr_src,
                                                  const float* __restrict__ dinv,
                                                  const float* __restrict__ b,
                                                  float* __restrict__ hout,
                                                  const int* __restrict__ batch,
                                                  float* __restrict__ gsum,
                                                  float* __restrict__ gmax) {
    __shared__ float sh[4][64];  // POOL only
    int tid = threadIdx.x;
    int node = blockIdx.x * 4 + (tid >> 6);   // grid exact: node < N_NODES always
    int lane = tid & 63;
    int grp = lane >> 3;   // 0..7 : which edge of the 8-wide batch
    int gl  = lane & 7;    // 0..7 : dims 8*gl .. 8*gl+7
    int s = row_ptr[node], e = row_ptr[node + 1];

    float acc[8] = {0.f, 0.f, 0.f, 0.f, 0.f, 0.f, 0.f, 0.f};
    for (int base = s; base < e; base += 64) {
        int nE = min(64, e - base);                                  // wave-uniform
        int msrc = (lane < nE) ? (int)csr_src[base + lane] : 0;      // coalesced u16
#pragma unroll
        for (int rr = 0; rr < 8; ++rr) {
            int i = rr * 8;
            if (i >= nE) break;                              // wave-uniform exit
            int myi = i + grp;                               // <= 63 always
            int src = __shfl(msrc, myi, 64);                 // full-exec shfl
            bool ok = myi < nE;
            int srcx = ok ? src : node;                      // safe, L2-hot fallback
            short8v v = *(const short8v*)&hw2[(size_t)srcx * 64 + gl * 8];
            if (ok) {
#pragma unroll
                for (int j = 0; j < 8; ++j) acc[j] += bf2f((unsigned short)v[j]);
            }
        }
    }
    // sum the 8 groups' partials (dims aligned across groups)
#pragma unroll
    for (int off = 8; off <= 32; off <<= 1) {
#pragma unroll
        for (int j = 0; j < 8; ++j) acc[j] += __shfl_xor(acc[j], off, 64);
    }
    // self-loop term (hw2 pre-scaled by dinv[row])
    short8v sv = *(const short8v*)&hw2[(size_t)node * 64 + gl * 8];
#pragma unroll
    for (int j = 0; j < 8; ++j) acc[j] += bf2f((unsigned short)sv[j]);

    float di = dinv[node];
    float4 b0 = *(const float4*)&b[gl * 8];
    float4 b1 = *(const float4*)&b[gl * 8 + 4];
    float val[8];
    val[0] = di * acc[0] + b0.x;
    val[1] = di * acc[1] + b0.y;
    val[2] = di * acc[2] + b0.z;
    val[3] = di * acc[3] + b0.w;
    val[4] = di * acc[4] + b1.x;
    val[5] = di * acc[5] + b1.y;
    val[6] = di * acc[6] + b1.z;
    val[7] = di * acc[7] + b1.w;

    float sq = 0.f;
#pragma unroll
    for (int j = 0; j < 8; ++j) sq += val[j] * val[j];
#pragma unroll
    for (int off = 1; off <= 4; off <<= 1) sq += __shfl_xor(sq, off, 64);
    float inv = 1.0f / fmaxf(sqrtf(sq), 1e-12f);

    if (POOL) {
        if (grp == 0) {
            float4 r0, r1;
            r0.x = fmaxf(val[0] * inv, 0.f);
            r0.y = fmaxf(val[1] * inv, 0.f);
            r0.z = fmaxf(val[2] * inv, 0.f);
            r0.w = fmaxf(val[3] * inv, 0.f);
            r1.x = fmaxf(val[4] * inv, 0.f);
            r1.y = fmaxf(val[5] * inv, 0.f);
            r1.z = fmaxf(val[6] * inv, 0.f);
            r1.w = fmaxf(val[7] * inv, 0.f);
            *(float4*)&sh[tid >> 6][gl * 8] = r0;
            *(float4*)&sh[tid >> 6][gl * 8 + 4] = r1;
        }
        __syncthreads();
        if (tid < 64) {
            int nb = blockIdx.x * 4;
            int gcur = batch[nb];
            float runsum = 0.f, runmax = 0.f;
#pragma unroll
            for (int w = 0; w < 4; ++w) {
                int g = batch[nb + w];
                if (g != gcur) {
                    atomicAdd(&gsum[gcur * 64 + tid], runsum);
                    atomicMax((int*)&gmax[gcur * 64 + tid], __float_as_int(runmax));
                    runsum = 0.f; runmax = 0.f; gcur = g;
                }
                float v = sh[w][tid];
                runsum += v;
                runmax = fmaxf(runmax, v);
            }
            atomicAdd(&gsum[gcur * 64 + tid], runsum);
            atomicMax((int*)&gmax[gcur * 64 + tid], __float_as_int(runmax));
        }
    } else {
        if (grp == 0) {
            float4 r0, r1;
            r0.x = fmaxf(val[0] * inv, 0.f);
            r0.y = fmaxf(val[1] * inv, 0.f);
            r0.z = fmaxf(val[2] * inv, 0.f);
            r0.w = fmaxf(val[3] * inv, 0.f);
            r1.x = fmaxf(val[4] * inv, 0.f);
            r1.y = fmaxf(val[5] * inv, 0.f);
            r1.z = fmaxf(val[6] * inv, 0.f);
            r1.w = fmaxf(val[7] * inv, 0.f);
            *(float4*)&hout[(size_t)node * 64 + gl * 8] = r0;
            *(float4*)&hout[(size_t)node * 64 + gl * 8 + 4] = r1;
        }
    }
}

// Phase-2: one block per graph; mean + concat + 128x32 linear.
__global__ __launch_bounds__(128) void linear_kernel(const float* __restrict__ gsum,
                                                     const float* __restrict__ gmax,
                                                     const int* __restrict__ gstart,
                                                     const float* __restrict__ Wl,
                                                     const float* __restrict__ bl,
                                                     float* __restrict__ out) {
    int g = blockIdx.x;
    __shared__ float pooled[128];
    int t = threadIdx.x;
    if (t < 64) {
        int cnt = gstart[g + 1] - gstart[g];
        pooled[t] = gsum[g * 64 + t] / fmaxf((float)cnt, 1.0f);
    } else {
        pooled[t] = gmax[g * 64 + (t - 64)];
    }
    __syncthreads();
    if (t < 32) {
        float acc = bl[t];
#pragma unroll 8
        for (int k = 0; k < 128; ++k) acc += pooled[k] * Wl[k * 32 + t];
        out[g * 32 + t] = acc;
    }
}

extern "C" void kernel_launch(void* const* d_in, const int* in_sizes, int n_in,
                              void* d_out, int out_size, void* d_ws, size_t ws_size,
                              hipStream_t stream) {
    const float* x        = (const float*)d_in[0];   // 50000 x 128
    const int*   ei       = (const int*)d_in[1];     // 2 x 800000
    const int*   batch    = (const int*)d_in[2];     // 50000
    const float* W1       = (const float*)d_in[3];   // 128 x 64
    const float* b1       = (const float*)d_in[4];
    const float* W2       = (const float*)d_in[5];   // 64 x 64
    const float* b2       = (const float*)d_in[6];
    const float* W3       = (const float*)d_in[7];   // 64 x 64
    const float* b3       = (const float*)d_in[8];
    const float* Wl       = (const float*)d_in[9];   // 128 x 32
    const float* bl       = (const float*)d_in[10];
    float* out = (float*)d_out;

    char* ws = (char*)d_ws;
    int*   cnt      = (int*)ws;                 ws += align256((size_t)N_NODES * 4);
    int*   incl     = (int*)ws;                 ws += align256((size_t)N_NODES * 4);
    int*   bsum     = (int*)ws;                 ws += align256((size_t)SCAN_NB * 4);
    int*   boff     = (int*)ws;                 ws += align256((size_t)SCAN_NB * 4);
    int*   row_ptr  = (int*)ws;                 ws += align256((size_t)(N_NODES + 1) * 4);
    int*   fill_ptr = (int*)ws;                 ws += align256((size_t)N_NODES * 4);
    float* dinv     = (float*)ws;               ws += align256((size_t)N_NODES * 4);
    int*   gstart   = (int*)ws;                 ws += align256((size_t)(N_GRAPHS + 1) * 4);
    float* gsum     = (float*)ws;               ws += (size_t)N_GRAPHS * 64 * 4;   // contiguous
    float* gmax     = (float*)ws;               ws += align256((size_t)N_GRAPHS * 64 * 4);
    unsigned short* csr_src = (unsigned short*)ws; ws += align256((size_t)N_EDGES * 2);
    unsigned short* hwb = (unsigned short*)ws;  ws += align256((size_t)N_NODES * 64 * 2);
    float* h1       = (float*)ws;               ws += align256((size_t)N_NODES * 64 * 4);
    float* h2       = (float*)ws;               ws += align256((size_t)N_NODES * 64 * 4);

    hipLaunchKernelGGL(zero2, dim3((N_NODES + 2 * N_GRAPHS * 64 + 255) / 256), dim3(256), 0,
                       stream, cnt, N_NODES, (int*)gsum, 2 * N_GRAPHS * 64);
    hipLaunchKernelGGL(deg_kernel, dim3((N_EDGES + 255) / 256), dim3(256), 0, stream, ei, cnt);
    hipLaunchKernelGGL(scan_a, dim3(SCAN_NB), dim3(256), 0, stream, cnt, incl, bsum);
    hipLaunchKernelGGL(scan_b_gstart, dim3(1), dim3(384), 0, stream, bsum, boff, batch, gstart);
    hipLaunchKernelGGL(scan_c, dim3(SCAN_NB), dim3(256), 0, stream,
                       cnt, incl, boff, row_ptr, fill_ptr, dinv);

    const int mm_grid = (N_NODES + 63) / 64;
    const int agg_grid = N_NODES / 4;  // exact: 12500 * 4 == 50000 (POOL needs no tail)

    // fill (CSR scatter, u16) and layer-1 matmul overlap in one dual-role launch
    hipLaunchKernelGGL(fill_mm1_kernel, dim3(MM1_BLOCKS + FILL_BLOCKS), dim3(256), 0, stream,
                       ei, fill_ptr, csr_src, x, W1, dinv, hwb);

    hipLaunchKernelGGL((agg_kernel<false>), dim3(agg_grid), dim3(256), 0, stream,
                       hwb, row_ptr, csr_src, dinv, b1, h1, batch, gsum, gmax);
    // layer 2
    hipLaunchKernelGGL((mfma_matmul<64>), dim3(mm_grid), dim3(256), 0, stream, h1, W2, dinv, hwb);
    hipLaunchKernelGGL((agg_kernel<false>), dim3(agg_grid), dim3(256), 0, stream,
                       hwb, row_ptr, csr_src, dinv, b2, h2, batch, gsum, gmax);
    // layer 3: matmul then fused agg+pool
    hipLaunchKernelGGL((mfma_matmul<64>), dim3(mm_grid), dim3(256), 0, stream, h2, W3, dinv, hwb);
    hipLaunchKernelGGL((agg_kernel<true>), dim3(agg_grid), dim3(256), 0, stream,
                       hwb, row_ptr, csr_src, dinv, b3, (float*)nullptr, batch, gsum, gmax);

    // final linear
    hipLaunchKernelGGL(linear_kernel, dim3(N_GRAPHS), dim3(128), 0, stream,
                       gsum, gmax, gstart, Wl, bl, out);
}

// Round 19
// 206.934 us; speedup vs baseline: 1.0702x; 1.0090x over previous
//
#include <hip/hip_runtime.h>
#include <hip/hip_bf16.h>

#define N_NODES 50000
#define N_EDGES 800000
#define N_GRAPHS 64
#define HID 64
#define SCAN_NB 196  // ceil(50000/256)
#define FILL_RANGES 8
#define RANGE_SIZE ((N_NODES + FILL_RANGES - 1) / FILL_RANGES)  // 6250
#define MM1_BLOCKS ((N_NODES + 63) / 64)                        // 782
#define FILL_BLOCKS (FILL_RANGES * ((N_EDGES + 255) / 256))     // 25000

static inline size_t align256(size_t x) { return (x + 255) & ~(size_t)255; }

typedef __attribute__((ext_vector_type(8))) short short8v;
typedef __attribute__((ext_vector_type(4))) float f32x4;

// bf16 helpers (bit-level, RNE) -- storage compression + MFMA input prep.
__device__ __forceinline__ unsigned short f2bf(float f) {
    unsigned int u = __float_as_uint(f);
    unsigned int r = (u + 0x7fffu + ((u >> 16) & 1u)) >> 16;
    return (unsigned short)r;
}
__device__ __forceinline__ float bf2f(unsigned short h) {
    return __uint_as_float(((unsigned int)h) << 16);
}

// zero two disjoint int ranges in one launch (cnt | gsum+gmax)
__global__ void zero2(int* __restrict__ a, int na, int* __restrict__ b, int nb) {
    int i = blockIdx.x * blockDim.x + threadIdx.x;
    if (i < na) a[i] = 0;
    else if (i < na + nb) b[i - na] = 0;
}

// count incoming edges per destination node
__global__ void deg_kernel(const int* __restrict__ ei, int* __restrict__ cnt) {
    int e = blockIdx.x * blockDim.x + threadIdx.x;
    if (e < N_EDGES) atomicAdd(&cnt[ei[N_EDGES + e]], 1);
}

// phase A: per-block (256-wide) inclusive scan of cnt; block totals to bsum
// (round-17 lesson: decoupled-lookback single-kernel scan serializes through
// a device-atomic chain, +14us; the 3 tiny grid-parallel launches win)
__global__ __launch_bounds__(256) void scan_a(const int* __restrict__ cnt,
                                              int* __restrict__ incl,
                                              int* __restrict__ bsum) {
    __shared__ int sd[256];
    int t = threadIdx.x;
    int i = blockIdx.x * 256 + t;
    int v = (i < N_NODES) ? cnt[i] : 0;
    sd[t] = v;
    __syncthreads();
    for (int off = 1; off < 256; off <<= 1) {
        int u = (t >= off) ? sd[t - off] : 0;
        __syncthreads();
        sd[t] += u;
        __syncthreads();
    }
    if (i < N_NODES) incl[i] = sd[t];
    if (t == 255) bsum[blockIdx.x] = sd[255];
}

// phase B (+gstart fused): threads 0..255 scan the block sums; threads
// 256..320 binary-search gstart (batch sorted). All threads hit every barrier.
__global__ __launch_bounds__(384) void scan_b_gstart(const int* __restrict__ bsum,
                                                     int* __restrict__ boff,
                                                     const int* __restrict__ batch,
                                                     int* __restrict__ gstart) {
    __shared__ int sd[256];
    int t = threadIdx.x;
    int v = 0;
    if (t < 256) {
        v = (t < SCAN_NB) ? bsum[t] : 0;
        sd[t] = v;
    }
    __syncthreads();
    for (int off = 1; off < 256; off <<= 1) {
        int u = (t < 256 && t >= off) ? sd[t - off] : 0;
        __syncthreads();
        if (t < 256) sd[t] += u;
        __syncthreads();
    }
    if (t < SCAN_NB) boff[t] = sd[t] - v;  // exclusive
    if (t >= 256 && t - 256 <= N_GRAPHS) {
        int g = t - 256;
        int lo = 0, hi = N_NODES;
        while (lo < hi) {
            int mid = (lo + hi) >> 1;
            if (batch[mid] < g) lo = mid + 1; else hi = mid;
        }
        gstart[g] = lo;
    }
}

// phase C: writeback row_ptr / fill_ptr / dinv
__global__ void scan_c(const int* __restrict__ cnt, const int* __restrict__ incl,
                       const int* __restrict__ boff, int* __restrict__ row_ptr,
                       int* __restrict__ fill_ptr, float* __restrict__ dinv) {
    int i = blockIdx.x * blockDim.x + threadIdx.x;
    if (i < N_NODES) {
        int c = cnt[i];
        int run = boff[i >> 8] + incl[i];  // inclusive prefix over all nodes
        row_ptr[i + 1] = run;
        fill_ptr[i] = run - c;             // bucket start
        dinv[i] = rsqrtf((float)c + 1.0f);
        if (i == 0) row_ptr[0] = 0;
    }
}

// DUAL-ROLE kernel: blocks [0, MM1_BLOCKS) run the layer-1 MFMA matmul;
// blocks [MM1_BLOCKS, ...) run the XCD-partitioned CSR scatter (round-8
// lesson: one csr region written from one XCD keeps lines L2-resident;
// class (bid-MM1_BLOCKS)&7 is a fixed bid%8 residue). csr_src is uint16.
// MM part: hw2 = bf16(dinv * (x @ W1)), 3-term hi/lo bf16 split; W fragments
// pre-swizzled in LDS; D layout (m89): row=(l>>4)*4+j, col=l&15.
__global__ __launch_bounds__(256) void fill_mm1_kernel(const int* __restrict__ ei,
                                                       int* __restrict__ fill_ptr,
                                                       unsigned short* __restrict__ csr_src,
                                                       const float* __restrict__ h,
                                                       const float* __restrict__ W,
                                                       const float* __restrict__ dinv,
                                                       unsigned short* __restrict__ hw2) {
    constexpr int K = 128;
    constexpr int NSTEP = K / 32;
    __shared__ unsigned short sWH[NSTEP * 4 * 64 * 8];
    __shared__ unsigned short sWL[NSTEP * 4 * 64 * 8];
    int tid = threadIdx.x;

    if (blockIdx.x >= MM1_BLOCKS) {
        // ---- fill role ----
        int fb = blockIdx.x - MM1_BLOCKS;
        int r = fb & (FILL_RANGES - 1);
        int e = (fb >> 3) * 256 + tid;
        if (e >= N_EDGES) return;
        int dst = ei[N_EDGES + e];
        int lo = r * RANGE_SIZE;
        if (dst >= lo && dst < lo + RANGE_SIZE) {
            int src = ei[e];
            int pos = atomicAdd(&fill_ptr[dst], 1);
            csr_src[pos] = (unsigned short)src;
        }
        return;
    }

    // ---- mm role ----
    int r0 = blockIdx.x * 64;
#pragma unroll 1
    for (int ent = tid; ent < NSTEP * 4 * 64; ent += 256) {
        int lane_e = ent & 63;
        int c = (ent >> 6) & 3;
        int step = ent >> 8;
        int kb = step * 32 + (lane_e >> 4) * 8;
        int n = c * 16 + (lane_e & 15);
#pragma unroll
        for (int j = 0; j < 8; ++j) {
            float f = W[(kb + j) * 64 + n];
            unsigned short hi = f2bf(f);
            sWH[ent * 8 + j] = hi;
            sWL[ent * 8 + j] = f2bf(f - bf2f(hi));
        }
    }
    __syncthreads();

    int lane = tid & 63;
    int wid = tid >> 6;
    int arow = min(r0 + wid * 16 + (lane & 15), N_NODES - 1);  // clamp; write guarded
    const float* ap = h + (size_t)arow * K;
    int klane = (lane >> 4) * 8;

    f32x4 acc[4];
#pragma unroll
    for (int c = 0; c < 4; ++c) acc[c] = (f32x4){0.f, 0.f, 0.f, 0.f};

#pragma unroll 1
    for (int step = 0; step < NSTEP; ++step) {
        int kb = step * 32 + klane;
        float4 f0 = *(const float4*)&ap[kb];
        float4 f1 = *(const float4*)&ap[kb + 4];
        float fv[8] = {f0.x, f0.y, f0.z, f0.w, f1.x, f1.y, f1.z, f1.w};
        short8v ahi, alo;
#pragma unroll
        for (int j = 0; j < 8; ++j) {
            unsigned short hi = f2bf(fv[j]);
            ahi[j] = (short)hi;
            alo[j] = (short)f2bf(fv[j] - bf2f(hi));
        }
#pragma unroll
        for (int c = 0; c < 4; ++c) {
            short8v bh = *(const short8v*)&sWH[((step * 4 + c) * 64 + lane) * 8];
            short8v bl = *(const short8v*)&sWL[((step * 4 + c) * 64 + lane) * 8];
            acc[c] = __builtin_amdgcn_mfma_f32_16x16x32_bf16(ahi, bh, acc[c], 0, 0, 0);
            acc[c] = __builtin_amdgcn_mfma_f32_16x16x32_bf16(alo, bh, acc[c], 0, 0, 0);
            acc[c] = __builtin_amdgcn_mfma_f32_16x16x32_bf16(ahi, bl, acc[c], 0, 0, 0);
        }
    }

    int rb = r0 + wid * 16 + (lane >> 4) * 4;
#pragma unroll
    for (int j = 0; j < 4; ++j) {
        int row = rb + j;
        if (row < N_NODES) {
            float dv = dinv[row];
#pragma unroll
            for (int c = 0; c < 4; ++c) {
                hw2[(size_t)row * 64 + c * 16 + (lane & 15)] = f2bf(dv * acc[c][j]);
            }
        }
    }
}

// FUSED agg + next-layer MFMA matmul. 1024 threads = 16 waves = 16 nodes
// (50000 = 3125*16 exact, no tail -> barrier-safe). Gather phase identical
// to agg_kernel (8-wide MLP-unrolled, round-14/16 lessons; wave-uniform shfl
// per round-5). Waves deposit normalized h rows into a 16x68-padded LDS tile
// (pad -> 2-way bank conflict = free), barrier, then waves 0-3 each compute
// one 16-col tile of h @ Wn via the SAME 3-term hi/lo MFMA as the standalone
// mm64 -- bit-identical arithmetic, so absmax unchanged. Round-12's fusion
// failed with a ~40us shfl matmul; the MFMA epilogue is ~1us of matrix-pipe.
// Eliminates the h f32 round-trip (25.6 MB/layer) and the mm64 launch.
__global__ __launch_bounds__(1024) void aggmm_kernel(const unsigned short* __restrict__ hw_in,
                                                     const int* __restrict__ row_ptr,
                                                     const unsigned short* __restrict__ csr_src,
                                                     const float* __restrict__ dinv,
                                                     const float* __restrict__ b,
                                                     const float* __restrict__ Wn,
                                                     unsigned short* __restrict__ hw_out) {
    __shared__ unsigned short sWH[2 * 4 * 64 * 8];  // 8 KB
    __shared__ unsigned short sWL[2 * 4 * 64 * 8];  // 8 KB
    __shared__ float hlds[16 * 68];                 // padded stride 68
    int tid = threadIdx.x;

    // stage Wn fragments (512 entries; threads 0..511 take one each)
    if (tid < 512) {
        int ent = tid;
        int lane_e = ent & 63;
        int c = (ent >> 6) & 3;
        int step = ent >> 8;
        int kb = step * 32 + (lane_e >> 4) * 8;
        int n = c * 16 + (lane_e & 15);
#pragma unroll
        for (int j = 0; j < 8; ++j) {
            float f = Wn[(kb + j) * 64 + n];
            unsigned short hi = f2bf(f);
            sWH[ent * 8 + j] = hi;
            sWL[ent * 8 + j] = f2bf(f - bf2f(hi));
        }
    }

    int wid = tid >> 6;                       // 0..15 = node within block
    int node = blockIdx.x * 16 + wid;         // grid exact: always < N_NODES
    int lane = tid & 63;
    int grp = lane >> 3;   // 0..7 : which edge of the 8-wide batch
    int gl  = lane & 7;    // 0..7 : dims 8*gl .. 8*gl+7
    int s = row_ptr[node], e = row_ptr[node + 1];

    float acc[8] = {0.f, 0.f, 0.f, 0.f, 0.f, 0.f, 0.f, 0.f};
    for (int base = s; base < e; base += 64) {
        int nE = min(64, e - base);                                  // wave-uniform
        int msrc = (lane < nE) ? (int)csr_src[base + lane] : 0;      // coalesced u16
#pragma unroll
        for (int rr = 0; rr < 8; ++rr) {
            int i = rr * 8;
            if (i >= nE) break;                              // wave-uniform exit
            int myi = i + grp;                               // <= 63 always
            int src = __shfl(msrc, myi, 64);                 // full-exec shfl
            bool ok = myi < nE;
            int srcx = ok ? src : node;                      // safe, L2-hot fallback
            short8v v = *(const short8v*)&hw_in[(size_t)srcx * 64 + gl * 8];
            if (ok) {
#pragma unroll
                for (int j = 0; j < 8; ++j) acc[j] += bf2f((unsigned short)v[j]);
            }
        }
    }
#pragma unroll
    for (int off = 8; off <= 32; off <<= 1) {
#pragma unroll
        for (int j = 0; j < 8; ++j) acc[j] += __shfl_xor(acc[j], off, 64);
    }
    short8v sv = *(const short8v*)&hw_in[(size_t)node * 64 + gl * 8];
#pragma unroll
    for (int j = 0; j < 8; ++j) acc[j] += bf2f((unsigned short)sv[j]);

    float di = dinv[node];
    float4 b0 = *(const float4*)&b[gl * 8];
    float4 b1 = *(const float4*)&b[gl * 8 + 4];
    float val[8];
    val[0] = di * acc[0] + b0.x;
    val[1] = di * acc[1] + b0.y;
    val[2] = di * acc[2] + b0.z;
    val[3] = di * acc[3] + b0.w;
    val[4] = di * acc[4] + b1.x;
    val[5] = di * acc[5] + b1.y;
    val[6] = di * acc[6] + b1.z;
    val[7] = di * acc[7] + b1.w;

    float sq = 0.f;
#pragma unroll
    for (int j = 0; j < 8; ++j) sq += val[j] * val[j];
#pragma unroll
    for (int off = 1; off <= 4; off <<= 1) sq += __shfl_xor(sq, off, 64);
    float inv = 1.0f / fmaxf(sqrtf(sq), 1e-12f);

    if (grp == 0) {
        float4 r0, r1;
        r0.x = fmaxf(val[0] * inv, 0.f);
        r0.y = fmaxf(val[1] * inv, 0.f);
        r0.z = fmaxf(val[2] * inv, 0.f);
        r0.w = fmaxf(val[3] * inv, 0.f);
        r1.x = fmaxf(val[4] * inv, 0.f);
        r1.y = fmaxf(val[5] * inv, 0.f);
        r1.z = fmaxf(val[6] * inv, 0.f);
        r1.w = fmaxf(val[7] * inv, 0.f);
        *(float4*)&hlds[wid * 68 + gl * 8] = r0;
        *(float4*)&hlds[wid * 68 + gl * 8 + 4] = r1;
    }
    __syncthreads();

    // ---- MFMA epilogue: waves 0-3, one 16-col tile each ----
    if (wid < 4) {
        int klane = (lane >> 4) * 8;
        f32x4 macc = (f32x4){0.f, 0.f, 0.f, 0.f};
#pragma unroll
        for (int step = 0; step < 2; ++step) {
            const float* hr = &hlds[(lane & 15) * 68 + step * 32 + klane];
            short8v ahi, alo;
#pragma unroll
            for (int j = 0; j < 8; ++j) {
                float f = hr[j];
                unsigned short hi = f2bf(f);
                ahi[j] = (short)hi;
                alo[j] = (short)f2bf(f - bf2f(hi));
            }
            short8v bh = *(const short8v*)&sWH[((step * 4 + wid) * 64 + lane) * 8];
            short8v bl = *(const short8v*)&sWL[((step * 4 + wid) * 64 + lane) * 8];
            macc = __builtin_amdgcn_mfma_f32_16x16x32_bf16(ahi, bh, macc, 0, 0, 0);
            macc = __builtin_amdgcn_mfma_f32_16x16x32_bf16(alo, bh, macc, 0, 0, 0);
            macc = __builtin_amdgcn_mfma_f32_16x16x32_bf16(ahi, bl, macc, 0, 0, 0);
        }
        int rb = blockIdx.x * 16 + (lane >> 4) * 4;
#pragma unroll
        for (int j = 0; j < 4; ++j) {
            int row = rb + j;
            hw_out[(size_t)row * 64 + wid * 16 + (lane & 15)] = f2bf(dinv[row] * macc[j]);
        }
    }
}

// Final agg (layer 3) + fused pooling: 256 threads, 4 nodes/block (grid
// exact N_NODES/4). Gather identical; block's 4 rows -> LDS, 64 threads
// run-combine per dim (batch sorted), ~1 atomicAdd+atomicMax per dim/block.
__global__ __launch_bounds__(256) void agg_pool_kernel(const unsigned short* __restrict__ hw2,
                                                       const int* __restrict__ row_ptr,
                                                       const unsigned short* __restrict__ csr_src,
                                                       const float* __restrict__ dinv,
                                                       const float* __restrict__ b,
                                                       const int* __restrict__ batch,
                                                       float* __restrict__ gsum,
                                                       float* __restrict__ gmax) {
    __shared__ float sh[4][64];
    int tid = threadIdx.x;
    int node = blockIdx.x * 4 + (tid >> 6);
    int lane = tid & 63;
    int grp = lane >> 3;
    int gl  = lane & 7;
    int s = row_ptr[node], e = row_ptr[node + 1];

    float acc[8] = {0.f, 0.f, 0.f, 0.f, 0.f, 0.f, 0.f, 0.f};
    for (int base = s; base < e; base += 64) {
        int nE = min(64, e - base);
        int msrc = (lane < nE) ? (int)csr_src[base + lane] : 0;
#pragma unroll
        for (int rr = 0; rr < 8; ++rr) {
            int i = rr * 8;
            if (i >= nE) break;
            int myi = i + grp;
            int src = __shfl(msrc, myi, 64);
            bool ok = myi < nE;
            int srcx = ok ? src : node;
            short8v v = *(const short8v*)&hw2[(size_t)srcx * 64 + gl * 8];
            if (ok) {
#pragma unroll
                for (int j = 0; j < 8; ++j) acc[j] += bf2f((unsigned short)v[j]);
            }
        }
    }
#pragma unroll
    for (int off = 8; off <= 32; off <<= 1) {
#pragma unroll
        for (int j = 0; j < 8; ++j) acc[j] += __shfl_xor(acc[j], off, 64);
    }
    short8v sv = *(const short8v*)&hw2[(size_t)node * 64 + gl * 8];
#pragma unroll
    for (int j = 0; j < 8; ++j) acc[j] += bf2f((unsigned short)sv[j]);

    float di = dinv[node];
    float4 b0 = *(const float4*)&b[gl * 8];
    float4 b1 = *(const float4*)&b[gl * 8 + 4];
    float val[8];
    val[0] = di * acc[0] + b0.x;
    val[1] = di * acc[1] + b0.y;
    val[2] = di * acc[2] + b0.z;
    val[3] = di * acc[3] + b0.w;
    val[4] = di * acc[4] + b1.x;
    val[5] = di * acc[5] + b1.y;
    val[6] = di * acc[6] + b1.z;
    val[7] = di * acc[7] + b1.w;

    float sq = 0.f;
#pragma unroll
    for (int j = 0; j < 8; ++j) sq += val[j] * val[j];
#pragma unroll
    for (int off = 1; off <= 4; off <<= 1) sq += __shfl_xor(sq, off, 64);
    float inv = 1.0f / fmaxf(sqrtf(sq), 1e-12f);

    if (grp == 0) {
        float4 r0, r1;
        r0.x = fmaxf(val[0] * inv, 0.f);
        r0.y = fmaxf(val[1] * inv, 0.f);
        r0.z = fmaxf(val[2] * inv, 0.f);
        r0.w = fmaxf(val[3] * inv, 0.f);
        r1.x = fmaxf(val[4] * inv, 0.f);
        r1.y = fmaxf(val[5] * inv, 0.f);
        r1.z = fmaxf(val[6] * inv, 0.f);
        r1.w = fmaxf(val[7] * inv, 0.f);
        *(float4*)&sh[tid >> 6][gl * 8] = r0;
        *(float4*)&sh[tid >> 6][gl * 8 + 4] = r1;
    }
    __syncthreads();
    if (tid < 64) {
        int nb = blockIdx.x * 4;
        int gcur = batch[nb];
        float runsum = 0.f, runmax = 0.f;
#pragma unroll
        for (int w = 0; w < 4; ++w) {
            int g = batch[nb + w];
            if (g != gcur) {
                atomicAdd(&gsum[gcur * 64 + tid], runsum);
                atomicMax((int*)&gmax[gcur * 64 + tid], __float_as_int(runmax));
                runsum = 0.f; runmax = 0.f; gcur = g;
            }
            float v = sh[w][tid];
            runsum += v;
            runmax = fmaxf(runmax, v);
        }
        atomicAdd(&gsum[gcur * 64 + tid], runsum);
        atomicMax((int*)&gmax[gcur * 64 + tid], __float_as_int(runmax));
    }
}

// Phase-2: one block per graph; mean + concat + 128x32 linear.
__global__ __launch_bounds__(128) void linear_kernel(const float* __restrict__ gsum,
                                                     const float* __restrict__ gmax,
                                                     const int* __restrict__ gstart,
                                                     const float* __restrict__ Wl,
                                                     const float* __restrict__ bl,
                                                     float* __restrict__ out) {
    int g = blockIdx.x;
    __shared__ float pooled[128];
    int t = threadIdx.x;
    if (t < 64) {
        int cnt = gstart[g + 1] - gstart[g];
        pooled[t] = gsum[g * 64 + t] / fmaxf((float)cnt, 1.0f);
    } else {
        pooled[t] = gmax[g * 64 + (t - 64)];
    }
    __syncthreads();
    if (t < 32) {
        float acc = bl[t];
#pragma unroll 8
        for (int k = 0; k < 128; ++k) acc += pooled[k] * Wl[k * 32 + t];
        out[g * 32 + t] = acc;
    }
}

extern "C" void kernel_launch(void* const* d_in, const int* in_sizes, int n_in,
                              void* d_out, int out_size, void* d_ws, size_t ws_size,
                              hipStream_t stream) {
    const float* x        = (const float*)d_in[0];   // 50000 x 128
    const int*   ei       = (const int*)d_in[1];     // 2 x 800000
    const int*   batch    = (const int*)d_in[2];     // 50000
    const float* W1       = (const float*)d_in[3];   // 128 x 64
    const float* b1       = (const float*)d_in[4];
    const float* W2       = (const float*)d_in[5];   // 64 x 64
    const float* b2       = (const float*)d_in[6];
    const float* W3       = (const float*)d_in[7];   // 64 x 64
    const float* b3       = (const float*)d_in[8];
    const float* Wl       = (const float*)d_in[9];   // 128 x 32
    const float* bl       = (const float*)d_in[10];
    float* out = (float*)d_out;

    char* ws = (char*)d_ws;
    int*   cnt      = (int*)ws;                 ws += align256((size_t)N_NODES * 4);
    int*   incl     = (int*)ws;                 ws += align256((size_t)N_NODES * 4);
    int*   bsum     = (int*)ws;                 ws += align256((size_t)SCAN_NB * 4);
    int*   boff     = (int*)ws;                 ws += align256((size_t)SCAN_NB * 4);
    int*   row_ptr  = (int*)ws;                 ws += align256((size_t)(N_NODES + 1) * 4);
    int*   fill_ptr = (int*)ws;                 ws += align256((size_t)N_NODES * 4);
    float* dinv     = (float*)ws;               ws += align256((size_t)N_NODES * 4);
    int*   gstart   = (int*)ws;                 ws += align256((size_t)(N_GRAPHS + 1) * 4);
    float* gsum     = (float*)ws;               ws += (size_t)N_GRAPHS * 64 * 4;   // contiguous
    float* gmax     = (float*)ws;               ws += align256((size_t)N_GRAPHS * 64 * 4);
    unsigned short* csr_src = (unsigned short*)ws; ws += align256((size_t)N_EDGES * 2);
    unsigned short* hwa = (unsigned short*)ws;  ws += align256((size_t)N_NODES * 64 * 2);
    unsigned short* hwb = (unsigned short*)ws;  ws += align256((size_t)N_NODES * 64 * 2);

    hipLaunchKernelGGL(zero2, dim3((N_NODES + 2 * N_GRAPHS * 64 + 255) / 256), dim3(256), 0,
                       stream, cnt, N_NODES, (int*)gsum, 2 * N_GRAPHS * 64);
    hipLaunchKernelGGL(deg_kernel, dim3((N_EDGES + 255) / 256), dim3(256), 0, stream, ei, cnt);
    hipLaunchKernelGGL(scan_a, dim3(SCAN_NB), dim3(256), 0, stream, cnt, incl, bsum);
    hipLaunchKernelGGL(scan_b_gstart, dim3(1), dim3(384), 0, stream, bsum, boff, batch, gstart);
    hipLaunchKernelGGL(scan_c, dim3(SCAN_NB), dim3(256), 0, stream,
                       cnt, incl, boff, row_ptr, fill_ptr, dinv);

    // fill (CSR scatter, u16) and layer-1 matmul overlap in one dual-role launch
    hipLaunchKernelGGL(fill_mm1_kernel, dim3(MM1_BLOCKS + FILL_BLOCKS), dim3(256), 0, stream,
                       ei, fill_ptr, csr_src, x, W1, dinv, hwa);

    const int aggmm_grid = N_NODES / 16;   // 3125, exact
    const int aggp_grid  = N_NODES / 4;    // 12500, exact

    // layer-1 agg + fused W2 matmul -> hwb
    hipLaunchKernelGGL(aggmm_kernel, dim3(aggmm_grid), dim3(1024), 0, stream,
                       hwa, row_ptr, csr_src, dinv, b1, W2, hwb);
    // layer-2 agg + fused W3 matmul -> hwa
    hipLaunchKernelGGL(aggmm_kernel, dim3(aggmm_grid), dim3(1024), 0, stream,
                       hwb, row_ptr, csr_src, dinv, b2, W3, hwa);
    // layer-3 agg + fused pooling
    hipLaunchKernelGGL(agg_pool_kernel, dim3(aggp_grid), dim3(256), 0, stream,
                       hwa, row_ptr, csr_src, dinv, b3, batch, gsum, gmax);

    // final linear
    hipLaunchKernelGGL(linear_kernel, dim3(N_GRAPHS), dim3(128), 0, stream,
                       gsum, gmax, gstart, Wl, bl, out);
}